// Round 10
// baseline (1765.036 us; speedup 1.0000x reference)
//
#include <hip/hip_runtime.h>

#define DIMX 3072
#define STX 512
#define SIX 1024
#define SQX 1536
#define FFX 12288

typedef __attribute__((ext_vector_type(4))) float f32x4;
typedef __attribute__((ext_vector_type(8))) __bf16 bf16x8;
typedef __attribute__((ext_vector_type(4))) int i32x4;
typedef __attribute__((ext_vector_type(4))) unsigned short u16x4;

__device__ __forceinline__ unsigned short f2bf(float f){
  unsigned u = __builtin_bit_cast(unsigned, f);
  u += 0x7FFFu + ((u>>16)&1u);
  return (unsigned short)(u>>16);
}
__device__ __forceinline__ unsigned short usbf(float x){
  return __builtin_bit_cast(unsigned short, (__bf16)x);
}
__device__ __forceinline__ float bf2f(unsigned short h){
  unsigned u = ((unsigned)h)<<16;
  return __builtin_bit_cast(float, u);
}
__device__ __forceinline__ float gelu_tanh(float x){
  float x3 = x*x*x;
  float z = 0.7978845608028654f*(x + 0.044715f*x3);
  z = fminf(fmaxf(z, -15.f), 15.f);
  float e = exp2f(z*2.8853900817779268f);   // e^(2z)
  float th = (e-1.f)/(e+1.f);
  return 0.5f*x*(1.f+th);
}

// async global->LDS, 16B per lane; lds base must be wave-uniform
__device__ __forceinline__ void gload16(const void* g, void* l){
  __builtin_amdgcn_global_load_lds(
      (const __attribute__((address_space(1))) void*)g,
      (__attribute__((address_space(3))) void*)l,
      16, 0, 0);
}

// ---------------- small kernels ----------------

__global__ void k_silu(const float* __restrict__ temb, float* __restrict__ out){
  int i = blockIdx.x*256 + threadIdx.x;
  if(i < DIMX){
    float x = temb[i];
    out[i] = x / (1.f + exp2f(-x*1.4426950408889634f));
  }
}

__global__ void k_modinit(const float* __restrict__ b_img, const float* __restrict__ b_txt,
                          float* __restrict__ mod){
  int idx = blockIdx.x*256 + threadIdx.x;   // 0..36863
  int mat = idx / 18432; int r = idx % 18432;
  int i = r/6, j = r%6;
  const float* b = mat ? b_txt : b_img;
  mod[mat*18432 + j*3072 + i] = b[r];
}

__global__ void k_modgemv(const float* __restrict__ w_img, const float* __restrict__ w_txt,
                          const float* __restrict__ silu_t, float* __restrict__ mod){
  int bz = blockIdx.x;
  int ks = bz & 7; bz >>= 3;
  int nc = bz % 18; int mat = bz / 18;
  const float* W = mat ? w_txt : w_img;
  __shared__ float st[384];
  int k0 = ks*384;
  for(int i = threadIdx.x; i < 384; i += 256) st[i] = silu_t[k0+i];
  __syncthreads();
  int n0 = nc*1024 + threadIdx.x*4;
  float ax=0.f, ay=0.f, az=0.f, aw=0.f;
  const float* Wp = W + (size_t)k0*18432 + n0;
  #pragma unroll 4
  for(int k=0;k<384;k++){
    float4 w = *(const float4*)(Wp + (size_t)k*18432);
    float s = st[k];
    ax += s*w.x; ay += s*w.y; az += s*w.z; aw += s*w.w;
  }
  float* md = mod + mat*18432;
  float vals[4] = {ax, ay, az, aw};
  #pragma unroll
  for(int j=0;j<4;j++){
    int n = n0+j; int i = n/6, jj = n%6;
    atomicAdd(&md[jj*3072 + i], vals[j]);
  }
}

// merged init: rows [0,R0) -> set0, rows [R0,..) -> set1; out = res + gate*bias
__global__ void k_initC2(float* __restrict__ out0, const float* __restrict__ res0,
                         const float* __restrict__ gate0, const float* __restrict__ bias0,
                         float* __restrict__ out1, const float* __restrict__ res1,
                         const float* __restrict__ gate1, const float* __restrict__ bias1,
                         int R0){
  long i = ((long)blockIdx.x*256 + threadIdx.x)*4;
  int row = (int)(i / 3072);
  int col = (int)(i % 3072);
  const float* res; const float* gate; const float* bias; float* out;
  long off;
  if(row < R0){ res=res0; gate=gate0; bias=bias0; out=out0; off=i; }
  else        { res=res1; gate=gate1; bias=bias1; out=out1; off=i - (long)R0*3072; }
  float4 r = *(const float4*)(res + off);
  float4 g = *(const float4*)(gate + col);
  float4 b = *(const float4*)(bias + col);
  float4 o = {r.x + g.x*b.x, r.y + g.y*b.y, r.z + g.z*b.z, r.w + g.w*b.w};
  *(float4*)(out + off) = o;
}

// merged LayerNorm+modulate: block < R0 -> set0 else set1
__global__ void k_lnmod2(const float* __restrict__ x0, const float* __restrict__ modp0,
                         unsigned short* __restrict__ out0,
                         const float* __restrict__ x1, const float* __restrict__ modp1,
                         unsigned short* __restrict__ out1, int R0){
  int row = blockIdx.x, t = threadIdx.x;
  const float* x; const float* modp; unsigned short* out;
  if(row < R0){ x=x0; modp=modp0; out=out0; }
  else        { x=x1; modp=modp1; out=out1; row -= R0; }
  const float* xr = x + (size_t)row*DIMX;
  float4 v0 = *(const float4*)(xr + t*4);
  float4 v1 = *(const float4*)(xr + 1024 + t*4);
  float4 v2 = *(const float4*)(xr + 2048 + t*4);
  float s  = v0.x+v0.y+v0.z+v0.w + v1.x+v1.y+v1.z+v1.w + v2.x+v2.y+v2.z+v2.w;
  float s2 = v0.x*v0.x+v0.y*v0.y+v0.z*v0.z+v0.w*v0.w
           + v1.x*v1.x+v1.y*v1.y+v1.z*v1.z+v1.w*v1.w
           + v2.x*v2.x+v2.y*v2.y+v2.z*v2.z+v2.w*v2.w;
  #pragma unroll
  for(int o=32;o>0;o>>=1){ s += __shfl_xor(s,o); s2 += __shfl_xor(s2,o); }
  __shared__ float rs_[4], rs2_[4];
  int wid = t>>6;
  if((t&63)==0){ rs_[wid]=s; rs2_[wid]=s2; }
  __syncthreads();
  float S  = rs_[0]+rs_[1]+rs_[2]+rs_[3];
  float S2 = rs2_[0]+rs2_[1]+rs2_[2]+rs2_[3];
  float mu = S*(1.f/3072.f);
  float var = S2*(1.f/3072.f) - mu*mu;
  float rstd = rsqrtf(var + 1e-6f);
  #pragma unroll
  for(int j=0;j<3;j++){
    int c = j*1024 + t*4;
    float4 sh = *(const float4*)(modp + c);
    float4 sc = *(const float4*)(modp + 3072 + c);
    float4 xv = (j==0)?v0:((j==1)?v1:v2);
    unsigned short h0 = f2bf((xv.x-mu)*rstd*(sc.x+1.f)+sh.x);
    unsigned short h1 = f2bf((xv.y-mu)*rstd*(sc.y+1.f)+sh.y);
    unsigned short h2 = f2bf((xv.z-mu)*rstd*(sc.z+1.f)+sh.z);
    unsigned short h3 = f2bf((xv.w-mu)*rstd*(sc.w+1.f)+sh.w);
    unsigned long long pk = (unsigned long long)(h0 | ((unsigned)h1<<16))
                          | ((unsigned long long)(h2 | ((unsigned)h3<<16))<<32);
    *(unsigned long long*)(out + (size_t)row*DIMX + c) = pk;
  }
}

// RMSNorm(q,k) + RoPE, V passthrough. grid (1536, 24), block 64.
__global__ void k_rmsrope(const unsigned short* __restrict__ qkv_txt,
                          const unsigned short* __restrict__ qkv_img,
                          const float* __restrict__ nqw, const float* __restrict__ nkw,
                          const float* __restrict__ naqw, const float* __restrict__ nakw,
                          const float* __restrict__ cosb, const float* __restrict__ sinb,
                          unsigned short* __restrict__ Q, unsigned short* __restrict__ K,
                          unsigned short* __restrict__ V){
  int s = blockIdx.x, h = blockIdx.y, t = threadIdx.x;
  bool txt = s < STX;
  const unsigned short* src = txt ? (qkv_txt + (size_t)s*9216)
                                  : (qkv_img + (size_t)(s-STX)*9216);
  const float* qw = txt ? naqw : nqw;
  const float* kw = txt ? nakw : nkw;
  int d0 = 2*t;
  float q1 = bf2f(src[h*128 + d0]),        q2 = bf2f(src[h*128 + d0 + 1]);
  float k1 = bf2f(src[3072 + h*128 + d0]), k2 = bf2f(src[3072 + h*128 + d0 + 1]);
  float v1 = bf2f(src[6144 + h*128 + d0]), v2 = bf2f(src[6144 + h*128 + d0 + 1]);
  float sq = q1*q1 + q2*q2, sk = k1*k1 + k2*k2;
  #pragma unroll
  for(int o=32;o>0;o>>=1){ sq += __shfl_xor(sq,o); sk += __shfl_xor(sk,o); }
  float rq = rsqrtf(sq*(1.f/128.f) + 1e-6f);
  float rk = rsqrtf(sk*(1.f/128.f) + 1e-6f);
  q1 *= rq*qw[d0]; q2 *= rq*qw[d0+1];
  k1 *= rk*kw[d0]; k2 *= rk*kw[d0+1];
  float c1 = cosb[(size_t)s*128 + d0], c2 = cosb[(size_t)s*128 + d0 + 1];
  float s1 = sinb[(size_t)s*128 + d0], s2 = sinb[(size_t)s*128 + d0 + 1];
  float Q1 = q1*c1 - q2*s1, Q2 = q2*c2 + q1*s2;
  float K1 = k1*c1 - k2*s1, K2 = k2*c2 + k1*s2;
  size_t o = ((size_t)s*24 + h)*128 + d0;
  Q[o] = f2bf(Q1); Q[o+1] = f2bf(Q2);
  K[o] = f2bf(K1); K[o+1] = f2bf(K2);
  V[o] = f2bf(v1); V[o+1] = f2bf(v2);
}

// V[s][h][d] -> VT[h][d][s]. grid (24 s-tiles, 24 heads), block 256.
__global__ void k_vtrans(const unsigned short* __restrict__ V, unsigned short* __restrict__ VT){
  __shared__ unsigned short tile[64][136];
  int st = blockIdx.x, h = blockIdx.y, t = threadIdx.x;
  int s0 = st*64;
  {
    int s = t>>2;
    #pragma unroll
    for(int i=0;i<4;i++){
      int oct = ((t&3)<<2) + i;     // 0..15
      i32x4 d = *(const i32x4*)(V + ((size_t)(s0+s)*24 + h)*128 + oct*8);
      *(i32x4*)&tile[s][oct*8] = d;
    }
  }
  __syncthreads();
  {
    int d0 = t>>3; int strip = t&7;
    #pragma unroll
    for(int i=0;i<4;i++){
      int d = d0 + i*32;
      unsigned short h8[8];
      #pragma unroll
      for(int j=0;j<8;j++) h8[j] = tile[strip*8 + j][d];
      unsigned a0 = h8[0] | ((unsigned)h8[1]<<16);
      unsigned a1 = h8[2] | ((unsigned)h8[3]<<16);
      unsigned a2 = h8[4] | ((unsigned)h8[5]<<16);
      unsigned a3 = h8[6] | ((unsigned)h8[7]<<16);
      i32x4 dv = {(int)a0,(int)a1,(int)a2,(int)a3};
      *(i32x4*)(VT + ((size_t)h*128 + d)*1536 + s0 + strip*8) = dv;
    }
  }
}

// ---------------- fused flash attention ----------------
// grid (12 q-blocks, 24 heads), 256 threads (4 waves); each wave owns 32 q rows.
__global__ __launch_bounds__(256,2) void k_fattn(
    const unsigned short* __restrict__ Q,
    const unsigned short* __restrict__ Kb,
    const unsigned short* __restrict__ VT,
    unsigned short* __restrict__ O)
{
  __shared__ unsigned short Kls[4][64][32];
  __shared__ unsigned short Vls[2][128][32];
  __shared__ unsigned short Pls[128][72];
  const int t = threadIdx.x;
  const int qb = blockIdx.x, h = blockIdx.y;
  const int lane = t&63, w = t>>6;
  const int lr = lane&15, lk = lane>>4;
  const float SC  = 0.08838834764831845f;
  const float L2E = 1.4426950408889634f;
  const int schunk = ((lane&3) ^ ((lane>>2)&3))*8;   // pre-swizzled source chunk
  const int rswz   = ((lr&3)<<3);                    // read-side XOR (shorts)

  bf16x8 qf[2][4];
  {
    const unsigned short* qp = Q + ((size_t)(qb*128 + w*32 + lr)*3072) + h*128 + lk*8;
    #pragma unroll
    for(int mf=0;mf<2;mf++)
      #pragma unroll
      for(int ks=0;ks<4;ks++)
        qf[mf][ks] = *(const bf16x8*)(qp + (size_t)mf*16*3072 + ks*32);
  }

  f32x4 o[2][8];
  #pragma unroll
  for(int i=0;i<2;i++)
    #pragma unroll
    for(int j=0;j<8;j++) o[i][j] = (f32x4){0.f,0.f,0.f,0.f};
  float mrow[2][4], lrow[2][4];
  #pragma unroll
  for(int i=0;i<2;i++)
    #pragma unroll
    for(int r=0;r<4;r++){ mrow[i][r] = -3.0e30f; lrow[i][r] = 0.f; }

  for(int kv0=0; kv0<SQX; kv0+=64){
    __syncthreads();
    {
      const unsigned short* kp = Kb + ((size_t)(kv0 + (lane>>2))*3072) + h*128 + w*32 + schunk;
      #pragma unroll
      for(int i=0;i<4;i++)
        gload16(kp + (size_t)i*16*3072, &Kls[w][i*16][0]);
    }
    {
      int c = w>>1;
      const unsigned short* vp = VT + ((size_t)(h*128 + (w&1)*64 + (lane>>2)))*1536 + kv0 + c*32 + schunk;
      #pragma unroll
      for(int j=0;j<4;j++)
        gload16(vp + (size_t)j*16*1536, &Vls[c][(w&1)*64 + j*16][0]);
    }
    __syncthreads();

    f32x4 s[2][4];
    #pragma unroll
    for(int mf=0;mf<2;mf++)
      #pragma unroll
      for(int nf=0;nf<4;nf++) s[mf][nf] = (f32x4){0.f,0.f,0.f,0.f};
    #pragma unroll
    for(int ks=0;ks<4;ks++){
      bf16x8 kf[4];
      #pragma unroll
      for(int nf=0;nf<4;nf++) kf[nf] = *(const bf16x8*)&Kls[ks][nf*16+lr][(lk*8) ^ rswz];
      #pragma unroll
      for(int mf=0;mf<2;mf++)
        #pragma unroll
        for(int nf=0;nf<4;nf++)
          s[mf][nf] = __builtin_amdgcn_mfma_f32_16x16x32_bf16(qf[mf][ks], kf[nf], s[mf][nf], 0,0,0);
    }

    #pragma unroll
    for(int mf=0;mf<2;mf++){
      #pragma unroll
      for(int r=0;r<4;r++){
        float v = fmaxf(fmaxf(s[mf][0][r], s[mf][1][r]), fmaxf(s[mf][2][r], s[mf][3][r]));
        #pragma unroll
        for(int d=1; d<16; d<<=1) v = fmaxf(v, __shfl_xor(v, d));
        float nm = fmaxf(mrow[mf][r], v*SC);
        float fac = exp2f((mrow[mf][r]-nm)*L2E);
        mrow[mf][r] = nm;
        float rs = 0.f;
        #pragma unroll
        for(int nf=0;nf<4;nf++){
          float p = exp2f((s[mf][nf][r]*SC - nm)*L2E);
          s[mf][nf][r] = p;
          rs += p;
        }
        #pragma unroll
        for(int d=1; d<16; d<<=1) rs += __shfl_xor(rs, d);
        lrow[mf][r] = lrow[mf][r]*fac + rs;
        #pragma unroll
        for(int nf=0;nf<8;nf++) o[mf][nf][r] *= fac;
      }
    }

    #pragma unroll
    for(int mf=0;mf<2;mf++)
      #pragma unroll
      for(int nf=0;nf<4;nf++)
        #pragma unroll
        for(int r=0;r<4;r++)
          Pls[w*32 + mf*16 + lk*4 + r][nf*16 + lr] = usbf(s[mf][nf][r]);

    #pragma unroll
    for(int ks2=0; ks2<2; ks2++){
      bf16x8 pa[2];
      #pragma unroll
      for(int mf=0;mf<2;mf++)
        pa[mf] = *(const bf16x8*)&Pls[w*32 + mf*16 + lr][ks2*32 + lk*8];
      #pragma unroll
      for(int nf=0;nf<8;nf++){
        bf16x8 vf = *(const bf16x8*)&Vls[ks2][nf*16+lr][(lk*8) ^ rswz];
        #pragma unroll
        for(int mf=0;mf<2;mf++)
          o[mf][nf] = __builtin_amdgcn_mfma_f32_16x16x32_bf16(pa[mf], vf, o[mf][nf], 0,0,0);
      }
    }
  }

  #pragma unroll
  for(int mf=0;mf<2;mf++){
    float inv[4];
    #pragma unroll
    for(int r=0;r<4;r++) inv[r] = 1.f/lrow[mf][r];
    #pragma unroll
    for(int nf=0;nf<8;nf++){
      #pragma unroll
      for(int r=0;r<4;r++){
        size_t row = (size_t)qb*128 + w*32 + mf*16 + lk*4 + r;
        size_t col = (size_t)h*128 + nf*16 + lr;
        O[row*3072 + col] = usbf(o[mf][nf][r]*inv[r]);
      }
    }
  }
}

// ---------------- merged MFMA GEMM, bf16 A, fp32 W[K][N] --------------------
// 2-tile-unrolled K loop, counted-vmcnt raw barriers: W loads for tile T+2 are
// issued each sub-iteration and stay in flight ACROSS the barrier (vmcnt(4)
// retires only the A global_load_lds, which is issued first, order pinned by
// sched_barrier). Kc must be a multiple of 64 (all call sites: 768/3072).
// mode 0: bf16 out (+bias)  mode 1: gelu -> bf16  mode 3: atomicAdd f32 gate*acc
__global__ __launch_bounds__(256,4) void k_gemmW(
    const unsigned short* __restrict__ A0, const unsigned short* __restrict__ A1, long lda,
    const float* __restrict__ W0, const float* __restrict__ W1, long ldw,
    const float* __restrict__ bias0, const float* __restrict__ bias1,
    void* __restrict__ C0, void* __restrict__ C1, long ldc,
    int nM0, int K, int KS, int mode,
    const float* __restrict__ gate0, const float* __restrict__ gate1)
{
  __shared__ unsigned short Als[2][128*32];   // 2 x 8 KB, source-swizzled granules
  __shared__ unsigned short Bls[2][128*40];   // 2 x 10 KB, padded bf16 B^T
  const int t = threadIdx.x;
  const int bn = blockIdx.x;
  int bm = blockIdx.y;
  const bool sel1 = (bm >= nM0);
  const unsigned short* A = sel1 ? A1 : A0;
  const float* W  = sel1 ? W1 : W0;
  const float* bias = sel1 ? bias1 : bias0;
  const float* gate = sel1 ? gate1 : gate0;
  void* Cp = sel1 ? C1 : C0;
  if(sel1) bm -= nM0;
  const int zs = blockIdx.z;
  const int Kc = K / KS, kbeg = zs*Kc, kend = kbeg + Kc;

  const unsigned short* Ab = A + (size_t)bm*128*lda;
  const float* Wb = W + (size_t)bn*128;

  const int lane = t & 63, wid = t>>6, wr = wid>>1, wc = wid&1;
  const int lr = lane & 15, lk = lane>>4;
  const int srow = (lane>>2);
  const int soff = (((lane&3) ^ ((lane>>3)&3))*8);   // pre-swizzled A source chunk
  const int aswz = ((lk ^ ((lr>>1)&3))*8);           // A read offset (shorts)
  const int u_ = t & 31;                             // W stage: n-group (4 cols)
  const int v_ = t >> 5;                             // W stage: k-group (4 rows)

  f32x4 acc[4][4];
  #pragma unroll
  for(int i=0;i<4;i++)
    #pragma unroll
    for(int j=0;j<4;j++) acc[i][j] = {0.f,0.f,0.f,0.f};

  float4 wE[4], wO[4];

#define GW_ISSUE_A(KT, DST) \
  gload16(Ab + (size_t)(     wid*16 + srow)*lda + (KT) + soff, (DST) + (     wid*16)*32); \
  gload16(Ab + (size_t)(64 + wid*16 + srow)*lda + (KT) + soff, (DST) + (64 + wid*16)*32);

#define GW_LOAD_W(KT, WS) \
  { _Pragma("unroll") \
    for(int j=0;j<4;j++) WS[j] = *(const float4*)(Wb + (size_t)((KT) + v_*4 + j)*ldw + u_*4); }

#define GW_PACK(WS, DST) \
  { _Pragma("unroll") \
    for(int i=0;i<4;i++){ \
      u16x4 pk = { usbf(WS[0][i]), usbf(WS[1][i]), usbf(WS[2][i]), usbf(WS[3][i]) }; \
      *(u16x4*)&(DST)[(u_*4+i)*40 + v_*4] = pk; \
    } }

#define GW_MFMA(ALS, BLS) \
  { bf16x8 af[4], bfr[4]; \
    _Pragma("unroll") \
    for(int mf=0;mf<4;mf++) af[mf]  = *(const bf16x8*)&(ALS)[(wr*64 + mf*16 + lr)*32 + aswz]; \
    _Pragma("unroll") \
    for(int nf=0;nf<4;nf++) bfr[nf] = *(const bf16x8*)&(BLS)[(wc*64 + nf*16 + lr)*40 + lk*8]; \
    _Pragma("unroll") \
    for(int mf=0;mf<4;mf++) \
      _Pragma("unroll") \
      for(int nf=0;nf<4;nf++) \
        acc[mf][nf] = __builtin_amdgcn_mfma_f32_16x16x32_bf16(af[mf], bfr[nf], acc[mf][nf], 0,0,0); }

  // ---- prologue ----
  GW_LOAD_W(kbeg, wE);
  GW_PACK(wE, Bls[0]);                 // reg-wait drains wE loads
  GW_ISSUE_A(kbeg, Als[0]);
  __builtin_amdgcn_sched_barrier(0);   // pin vm order: A before wO
  GW_LOAD_W(kbeg+32, wO);
  asm volatile("s_waitcnt vmcnt(4) lgkmcnt(0)" ::: "memory");  // retire A, keep wO flying
  __builtin_amdgcn_s_barrier();

  for(int k0=kbeg; k0<kend; k0+=64){
    // ---- sub-iter E: tile k0 from buf0; wO holds W(k0+32) ----
    {
      GW_ISSUE_A(k0+32, Als[1]);
      __builtin_amdgcn_sched_barrier(0);
      const bool hW = (k0+64 < kend);
      if(hW){ GW_LOAD_W(k0+64, wE); }
      GW_MFMA(Als[0], Bls[0]);
      GW_PACK(wO, Bls[1]);
      if(hW) asm volatile("s_waitcnt vmcnt(4) lgkmcnt(0)" ::: "memory");
      else   asm volatile("s_waitcnt vmcnt(0) lgkmcnt(0)" ::: "memory");
      __builtin_amdgcn_s_barrier();
    }
    // ---- sub-iter O: tile k0+32 from buf1; wE holds W(k0+64) if it exists ----
    {
      const bool hA = (k0+64 < kend);
      const bool hW2 = (k0+96 < kend);
      if(hA){
        GW_ISSUE_A(k0+64, Als[0]);
        __builtin_amdgcn_sched_barrier(0);
      }
      if(hW2){ GW_LOAD_W(k0+96, wO); }
      GW_MFMA(Als[1], Bls[1]);
      if(hA){
        GW_PACK(wE, Bls[0]);
        if(hW2) asm volatile("s_waitcnt vmcnt(4) lgkmcnt(0)" ::: "memory");
        else    asm volatile("s_waitcnt vmcnt(0) lgkmcnt(0)" ::: "memory");
        __builtin_amdgcn_s_barrier();
      }
    }
  }

#undef GW_ISSUE_A
#undef GW_LOAD_W
#undef GW_PACK
#undef GW_MFMA

  unsigned short* C16 = (unsigned short*)Cp;
  float* C32 = (float*)Cp;
  #pragma unroll
  for(int mf=0;mf<4;mf++){
    #pragma unroll
    for(int nf=0;nf<4;nf++){
      #pragma unroll
      for(int r=0;r<4;r++){
        size_t row = (size_t)bm*128 + wr*64 + mf*16 + lk*4 + r;
        size_t col = (size_t)bn*128 + wc*64 + nf*16 + lr;
        float v2 = acc[mf][nf][r];
        if(mode==0){
          C16[row*ldc + col] = f2bf(v2 + (bias ? bias[col] : 0.f));
        } else if(mode==1){
          C16[row*ldc + col] = f2bf(gelu_tanh(v2 + (bias ? bias[col] : 0.f)));
        } else {
          float g = gate ? gate[col] : 1.f;
          atomicAdd(&C32[row*ldc + col], g*v2);
        }
      }
    }
  }
}

// ---------------- launch ----------------

extern "C" void kernel_launch(void* const* d_in, const int* in_sizes, int n_in,
                              void* d_out, int out_size, void* d_ws, size_t ws_size,
                              hipStream_t stream){
  const float* hidden_states = (const float*)d_in[0];
  const float* enc_states    = (const float*)d_in[1];
  const float* temb          = (const float*)d_in[3];
  const float* rope_cos      = (const float*)d_in[4];
  const float* rope_sin      = (const float*)d_in[5];
  const float* w_img_mod     = (const float*)d_in[6];
  const float* b_img_mod     = (const float*)d_in[7];
  const float* w_txt_mod     = (const float*)d_in[8];
  const float* b_txt_mod     = (const float*)d_in[9];
  const float* norm_q_w      = (const float*)d_in[10];
  const float* norm_k_w      = (const float*)d_in[11];
  const float* norm_aq_w     = (const float*)d_in[12];
  const float* norm_ak_w     = (const float*)d_in[13];
  const float* w_qkv   = (const float*)d_in[14];
  const float* b_qkv   = (const float*)d_in[15];
  const float* w_aqkv  = (const float*)d_in[16];
  const float* b_aqkv  = (const float*)d_in[17];
  const float* w_out_  = (const float*)d_in[18];
  const float* b_out_  = (const float*)d_in[19];
  const float* w_aout  = (const float*)d_in[20];
  const float* b_aout  = (const float*)d_in[21];
  const float* w_mlp1i = (const float*)d_in[22];
  const float* b_mlp1i = (const float*)d_in[23];
  const float* w_mlp2i = (const float*)d_in[24];
  const float* b_mlp2i = (const float*)d_in[25];
  const float* w_mlp1t = (const float*)d_in[26];
  const float* b_mlp1t = (const float*)d_in[27];
  const float* w_mlp2t = (const float*)d_in[28];
  const float* b_mlp2t = (const float*)d_in[29];

  char* ws = (char*)d_ws;
  float* mod    = (float*)(ws + 0);                        // 2*6*3072 f32
  float* silu_t = (float*)(ws + 147456);
  unsigned short* imgm = (unsigned short*)(ws + 159744);   // 1024x3072 bf16
  unsigned short* txtm = (unsigned short*)(ws + 6451200);  // 512x3072 bf16
  float* hid = (float*)(ws + 9596928);                     // 1024x3072 f32
  float* enc = (float*)(ws + 22179840);                    // 512x3072 f32
  unsigned short* Qb  = (unsigned short*)(ws + 47345664);  // 1536x3072 bf16
  unsigned short* Kb  = (unsigned short*)(ws + 56782848);
  unsigned short* Vb  = (unsigned short*)(ws + 66220032);  // dead after vtrans
  unsigned short* attnb = (unsigned short*)(ws + 66220032);// 1536x3072 bf16 (reuses Vb)
  unsigned short* VTb = (unsigned short*)(ws + 75657216);  // 24x128x1536 bf16
  unsigned short* mlphI = (unsigned short*)(ws + 103968768);// 1024x12288 bf16
  unsigned short* mlphT = (unsigned short*)(ws + 129134592);// 512x12288 bf16
  unsigned short* qkvi = (unsigned short*)(ws + 141717504);// 1024x9216 bf16
  unsigned short* qkvt = (unsigned short*)(ws + 160591872);// 512x9216 bf16

  float* out_enc = (float*)d_out;
  float* out_hid = (float*)d_out + (size_t)STX*DIMX;

  // modulation params
  k_silu<<<12,256,0,stream>>>(temb, silu_t);
  k_modinit<<<144,256,0,stream>>>(b_img_mod, b_txt_mod, mod);
  k_modgemv<<<288,256,0,stream>>>(w_img_mod, w_txt_mod, silu_t, mod);

  // LN + modulate (mod1), img+txt merged
  k_lnmod2<<<SQX,256,0,stream>>>(hidden_states, mod + 0, imgm,
                                 enc_states, mod + 18432, txtm, SIX);

  // QKV projections, img+txt merged (fp32 weights consumed directly)
  k_gemmW<<<dim3(72,12,1),256,0,stream>>>(imgm, txtm, 3072,
      w_qkv, w_aqkv, 9216, b_qkv, b_aqkv,
      qkvi, qkvt, 9216, 8, 3072,1, 0, nullptr,nullptr);

  // RMS + RoPE -> Q,K,V [1536][24][128]; V transpose
  k_rmsrope<<<dim3(1536,24),64,0,stream>>>(qkvt, qkvi, norm_q_w, norm_k_w,
      norm_aq_w, norm_ak_w, rope_cos, rope_sin, Qb, Kb, Vb);
  k_vtrans<<<dim3(24,24),256,0,stream>>>(Vb, VTb);

  // fused flash attention -> attnb bf16
  k_fattn<<<dim3(12,24),256,0,stream>>>(Qb, Kb, VTb, attnb);

  // residual+gate1 inits, then merged out-projections (split-K atomics)
  k_initC2<<<4608,256,0,stream>>>(hid, hidden_states, mod + 2*3072, b_out_,
                                  enc, enc_states, mod + 18432 + 2*3072, b_aout, SIX);
  k_gemmW<<<dim3(24,12,4),256,0,stream>>>(attnb + (size_t)512*3072, attnb, 3072,
      w_out_, w_aout, 3072, nullptr, nullptr,
      hid, enc, 3072, 8, 3072,4, 3, mod + 2*3072, mod + 18432 + 2*3072);

  // LN + modulate (mod2), merged
  k_lnmod2<<<SQX,256,0,stream>>>(hid, mod + 3*3072, imgm,
                                 enc, mod + 18432 + 3*3072, txtm, SIX);

  // MLP1 merged (gelu epilogue)
  k_gemmW<<<dim3(96,12,1),256,0,stream>>>(imgm, txtm, 3072,
      w_mlp1i, w_mlp1t, 12288, b_mlp1i, b_mlp1t,
      mlphI, mlphT, 12288, 8, 3072,1, 1, nullptr,nullptr);

  // output inits, then MLP2 merged (split-K atomics into d_out)
  k_initC2<<<4608,256,0,stream>>>(out_hid, hid, mod + 5*3072, b_mlp2i,
                                  out_enc, enc, mod + 18432 + 5*3072, b_mlp2t, SIX);
  k_gemmW<<<dim3(24,12,4),256,0,stream>>>(mlphI, mlphT, 12288,
      w_mlp2i, w_mlp2t, 3072, nullptr, nullptr,
      out_hid, out_enc, 3072, 8, 12288,4, 3, mod + 5*3072, mod + 18432 + 5*3072);
}

// Round 11
// 1122.959 us; speedup vs baseline: 1.5718x; 1.5718x over previous
//
#include <hip/hip_runtime.h>

#define DIMX 3072
#define STX 512
#define SIX 1024
#define SQX 1536
#define FFX 12288

typedef __attribute__((ext_vector_type(4))) float f32x4;
typedef __attribute__((ext_vector_type(8))) __bf16 bf16x8;
typedef __attribute__((ext_vector_type(4))) int i32x4;
typedef __attribute__((ext_vector_type(4))) unsigned short u16x4;

__device__ __forceinline__ unsigned short f2bf(float f){
  unsigned u = __builtin_bit_cast(unsigned, f);
  u += 0x7FFFu + ((u>>16)&1u);
  return (unsigned short)(u>>16);
}
__device__ __forceinline__ unsigned short usbf(float x){
  return __builtin_bit_cast(unsigned short, (__bf16)x);
}
__device__ __forceinline__ float bf2f(unsigned short h){
  unsigned u = ((unsigned)h)<<16;
  return __builtin_bit_cast(float, u);
}
__device__ __forceinline__ float gelu_tanh(float x){
  float x3 = x*x*x;
  float z = 0.7978845608028654f*(x + 0.044715f*x3);
  z = fminf(fmaxf(z, -15.f), 15.f);
  float e = exp2f(z*2.8853900817779268f);   // e^(2z)
  float th = (e-1.f)/(e+1.f);
  return 0.5f*x*(1.f+th);
}

// async global->LDS, 16B per lane; lds base must be wave-uniform
__device__ __forceinline__ void gload16(const void* g, void* l){
  __builtin_amdgcn_global_load_lds(
      (const __attribute__((address_space(1))) void*)g,
      (__attribute__((address_space(3))) void*)l,
      16, 0, 0);
}

// ---------------- small kernels ----------------

__global__ void k_silu(const float* __restrict__ temb, float* __restrict__ out){
  int i = blockIdx.x*256 + threadIdx.x;
  if(i < DIMX){
    float x = temb[i];
    out[i] = x / (1.f + exp2f(-x*1.4426950408889634f));
  }
}

__global__ void k_modinit(const float* __restrict__ b_img, const float* __restrict__ b_txt,
                          float* __restrict__ mod){
  int idx = blockIdx.x*256 + threadIdx.x;   // 0..36863
  int mat = idx / 18432; int r = idx % 18432;
  int i = r/6, j = r%6;
  const float* b = mat ? b_txt : b_img;
  mod[mat*18432 + j*3072 + i] = b[r];
}

__global__ void k_modgemv(const float* __restrict__ w_img, const float* __restrict__ w_txt,
                          const float* __restrict__ silu_t, float* __restrict__ mod){
  int bz = blockIdx.x;
  int ks = bz & 7; bz >>= 3;
  int nc = bz % 18; int mat = bz / 18;
  const float* W = mat ? w_txt : w_img;
  __shared__ float st[384];
  int k0 = ks*384;
  for(int i = threadIdx.x; i < 384; i += 256) st[i] = silu_t[k0+i];
  __syncthreads();
  int n0 = nc*1024 + threadIdx.x*4;
  float ax=0.f, ay=0.f, az=0.f, aw=0.f;
  const float* Wp = W + (size_t)k0*18432 + n0;
  #pragma unroll 4
  for(int k=0;k<384;k++){
    float4 w = *(const float4*)(Wp + (size_t)k*18432);
    float s = st[k];
    ax += s*w.x; ay += s*w.y; az += s*w.z; aw += s*w.w;
  }
  float* md = mod + mat*18432;
  float vals[4] = {ax, ay, az, aw};
  #pragma unroll
  for(int j=0;j<4;j++){
    int n = n0+j; int i = n/6, jj = n%6;
    atomicAdd(&md[jj*3072 + i], vals[j]);
  }
}

// merged init: rows [0,R0) -> set0, rows [R0,..) -> set1; out = res + gate*bias
__global__ void k_initC2(float* __restrict__ out0, const float* __restrict__ res0,
                         const float* __restrict__ gate0, const float* __restrict__ bias0,
                         float* __restrict__ out1, const float* __restrict__ res1,
                         const float* __restrict__ gate1, const float* __restrict__ bias1,
                         int R0){
  long i = ((long)blockIdx.x*256 + threadIdx.x)*4;
  int row = (int)(i / 3072);
  int col = (int)(i % 3072);
  const float* res; const float* gate; const float* bias; float* out;
  long off;
  if(row < R0){ res=res0; gate=gate0; bias=bias0; out=out0; off=i; }
  else        { res=res1; gate=gate1; bias=bias1; out=out1; off=i - (long)R0*3072; }
  float4 r = *(const float4*)(res + off);
  float4 g = *(const float4*)(gate + col);
  float4 b = *(const float4*)(bias + col);
  float4 o = {r.x + g.x*b.x, r.y + g.y*b.y, r.z + g.z*b.z, r.w + g.w*b.w};
  *(float4*)(out + off) = o;
}

// merged LayerNorm+modulate: block < R0 -> set0 else set1
__global__ void k_lnmod2(const float* __restrict__ x0, const float* __restrict__ modp0,
                         unsigned short* __restrict__ out0,
                         const float* __restrict__ x1, const float* __restrict__ modp1,
                         unsigned short* __restrict__ out1, int R0){
  int row = blockIdx.x, t = threadIdx.x;
  const float* x; const float* modp; unsigned short* out;
  if(row < R0){ x=x0; modp=modp0; out=out0; }
  else        { x=x1; modp=modp1; out=out1; row -= R0; }
  const float* xr = x + (size_t)row*DIMX;
  float4 v0 = *(const float4*)(xr + t*4);
  float4 v1 = *(const float4*)(xr + 1024 + t*4);
  float4 v2 = *(const float4*)(xr + 2048 + t*4);
  float s  = v0.x+v0.y+v0.z+v0.w + v1.x+v1.y+v1.z+v1.w + v2.x+v2.y+v2.z+v2.w;
  float s2 = v0.x*v0.x+v0.y*v0.y+v0.z*v0.z+v0.w*v0.w
           + v1.x*v1.x+v1.y*v1.y+v1.z*v1.z+v1.w*v1.w
           + v2.x*v2.x+v2.y*v2.y+v2.z*v2.z+v2.w*v2.w;
  #pragma unroll
  for(int o=32;o>0;o>>=1){ s += __shfl_xor(s,o); s2 += __shfl_xor(s2,o); }
  __shared__ float rs_[4], rs2_[4];
  int wid = t>>6;
  if((t&63)==0){ rs_[wid]=s; rs2_[wid]=s2; }
  __syncthreads();
  float S  = rs_[0]+rs_[1]+rs_[2]+rs_[3];
  float S2 = rs2_[0]+rs2_[1]+rs2_[2]+rs2_[3];
  float mu = S*(1.f/3072.f);
  float var = S2*(1.f/3072.f) - mu*mu;
  float rstd = rsqrtf(var + 1e-6f);
  #pragma unroll
  for(int j=0;j<3;j++){
    int c = j*1024 + t*4;
    float4 sh = *(const float4*)(modp + c);
    float4 sc = *(const float4*)(modp + 3072 + c);
    float4 xv = (j==0)?v0:((j==1)?v1:v2);
    unsigned short h0 = f2bf((xv.x-mu)*rstd*(sc.x+1.f)+sh.x);
    unsigned short h1 = f2bf((xv.y-mu)*rstd*(sc.y+1.f)+sh.y);
    unsigned short h2 = f2bf((xv.z-mu)*rstd*(sc.z+1.f)+sh.z);
    unsigned short h3 = f2bf((xv.w-mu)*rstd*(sc.w+1.f)+sh.w);
    unsigned long long pk = (unsigned long long)(h0 | ((unsigned)h1<<16))
                          | ((unsigned long long)(h2 | ((unsigned)h3<<16))<<32);
    *(unsigned long long*)(out + (size_t)row*DIMX + c) = pk;
  }
}

// RMSNorm(q,k) + RoPE, V passthrough. grid (1536, 24), block 64.
__global__ void k_rmsrope(const unsigned short* __restrict__ qkv_txt,
                          const unsigned short* __restrict__ qkv_img,
                          const float* __restrict__ nqw, const float* __restrict__ nkw,
                          const float* __restrict__ naqw, const float* __restrict__ nakw,
                          const float* __restrict__ cosb, const float* __restrict__ sinb,
                          unsigned short* __restrict__ Q, unsigned short* __restrict__ K,
                          unsigned short* __restrict__ V){
  int s = blockIdx.x, h = blockIdx.y, t = threadIdx.x;
  bool txt = s < STX;
  const unsigned short* src = txt ? (qkv_txt + (size_t)s*9216)
                                  : (qkv_img + (size_t)(s-STX)*9216);
  const float* qw = txt ? naqw : nqw;
  const float* kw = txt ? nakw : nkw;
  int d0 = 2*t;
  float q1 = bf2f(src[h*128 + d0]),        q2 = bf2f(src[h*128 + d0 + 1]);
  float k1 = bf2f(src[3072 + h*128 + d0]), k2 = bf2f(src[3072 + h*128 + d0 + 1]);
  float v1 = bf2f(src[6144 + h*128 + d0]), v2 = bf2f(src[6144 + h*128 + d0 + 1]);
  float sq = q1*q1 + q2*q2, sk = k1*k1 + k2*k2;
  #pragma unroll
  for(int o=32;o>0;o>>=1){ sq += __shfl_xor(sq,o); sk += __shfl_xor(sk,o); }
  float rq = rsqrtf(sq*(1.f/128.f) + 1e-6f);
  float rk = rsqrtf(sk*(1.f/128.f) + 1e-6f);
  q1 *= rq*qw[d0]; q2 *= rq*qw[d0+1];
  k1 *= rk*kw[d0]; k2 *= rk*kw[d0+1];
  float c1 = cosb[(size_t)s*128 + d0], c2 = cosb[(size_t)s*128 + d0 + 1];
  float s1 = sinb[(size_t)s*128 + d0], s2 = sinb[(size_t)s*128 + d0 + 1];
  float Q1 = q1*c1 - q2*s1, Q2 = q2*c2 + q1*s2;
  float K1 = k1*c1 - k2*s1, K2 = k2*c2 + k1*s2;
  size_t o = ((size_t)s*24 + h)*128 + d0;
  Q[o] = f2bf(Q1); Q[o+1] = f2bf(Q2);
  K[o] = f2bf(K1); K[o+1] = f2bf(K2);
  V[o] = f2bf(v1); V[o+1] = f2bf(v2);
}

// V[s][h][d] -> VT[h][d][s]. grid (24 s-tiles, 24 heads), block 256.
__global__ void k_vtrans(const unsigned short* __restrict__ V, unsigned short* __restrict__ VT){
  __shared__ unsigned short tile[64][136];
  int st = blockIdx.x, h = blockIdx.y, t = threadIdx.x;
  int s0 = st*64;
  {
    int s = t>>2;
    #pragma unroll
    for(int i=0;i<4;i++){
      int oct = ((t&3)<<2) + i;     // 0..15
      i32x4 d = *(const i32x4*)(V + ((size_t)(s0+s)*24 + h)*128 + oct*8);
      *(i32x4*)&tile[s][oct*8] = d;
    }
  }
  __syncthreads();
  {
    int d0 = t>>3; int strip = t&7;
    #pragma unroll
    for(int i=0;i<4;i++){
      int d = d0 + i*32;
      unsigned short h8[8];
      #pragma unroll
      for(int j=0;j<8;j++) h8[j] = tile[strip*8 + j][d];
      unsigned a0 = h8[0] | ((unsigned)h8[1]<<16);
      unsigned a1 = h8[2] | ((unsigned)h8[3]<<16);
      unsigned a2 = h8[4] | ((unsigned)h8[5]<<16);
      unsigned a3 = h8[6] | ((unsigned)h8[7]<<16);
      i32x4 dv = {(int)a0,(int)a1,(int)a2,(int)a3};
      *(i32x4*)(VT + ((size_t)h*128 + d)*1536 + s0 + strip*8) = dv;
    }
  }
}

// ---------------- fused flash attention ----------------
// grid (12 q-blocks, 24 heads), 256 threads (4 waves); each wave owns 32 q rows.
__global__ __launch_bounds__(256,2) void k_fattn(
    const unsigned short* __restrict__ Q,
    const unsigned short* __restrict__ Kb,
    const unsigned short* __restrict__ VT,
    unsigned short* __restrict__ O)
{
  __shared__ unsigned short Kls[4][64][32];
  __shared__ unsigned short Vls[2][128][32];
  __shared__ unsigned short Pls[128][72];
  const int t = threadIdx.x;
  const int qb = blockIdx.x, h = blockIdx.y;
  const int lane = t&63, w = t>>6;
  const int lr = lane&15, lk = lane>>4;
  const float SC  = 0.08838834764831845f;
  const float L2E = 1.4426950408889634f;
  const int schunk = ((lane&3) ^ ((lane>>2)&3))*8;   // pre-swizzled source chunk
  const int rswz   = ((lr&3)<<3);                    // read-side XOR (shorts)

  bf16x8 qf[2][4];
  {
    const unsigned short* qp = Q + ((size_t)(qb*128 + w*32 + lr)*3072) + h*128 + lk*8;
    #pragma unroll
    for(int mf=0;mf<2;mf++)
      #pragma unroll
      for(int ks=0;ks<4;ks++)
        qf[mf][ks] = *(const bf16x8*)(qp + (size_t)mf*16*3072 + ks*32);
  }

  f32x4 o[2][8];
  #pragma unroll
  for(int i=0;i<2;i++)
    #pragma unroll
    for(int j=0;j<8;j++) o[i][j] = (f32x4){0.f,0.f,0.f,0.f};
  float mrow[2][4], lrow[2][4];
  #pragma unroll
  for(int i=0;i<2;i++)
    #pragma unroll
    for(int r=0;r<4;r++){ mrow[i][r] = -3.0e30f; lrow[i][r] = 0.f; }

  for(int kv0=0; kv0<SQX; kv0+=64){
    __syncthreads();
    {
      const unsigned short* kp = Kb + ((size_t)(kv0 + (lane>>2))*3072) + h*128 + w*32 + schunk;
      #pragma unroll
      for(int i=0;i<4;i++)
        gload16(kp + (size_t)i*16*3072, &Kls[w][i*16][0]);
    }
    {
      int c = w>>1;
      const unsigned short* vp = VT + ((size_t)(h*128 + (w&1)*64 + (lane>>2)))*1536 + kv0 + c*32 + schunk;
      #pragma unroll
      for(int j=0;j<4;j++)
        gload16(vp + (size_t)j*16*1536, &Vls[c][(w&1)*64 + j*16][0]);
    }
    __syncthreads();

    f32x4 s[2][4];
    #pragma unroll
    for(int mf=0;mf<2;mf++)
      #pragma unroll
      for(int nf=0;nf<4;nf++) s[mf][nf] = (f32x4){0.f,0.f,0.f,0.f};
    #pragma unroll
    for(int ks=0;ks<4;ks++){
      bf16x8 kf[4];
      #pragma unroll
      for(int nf=0;nf<4;nf++) kf[nf] = *(const bf16x8*)&Kls[ks][nf*16+lr][(lk*8) ^ rswz];
      #pragma unroll
      for(int mf=0;mf<2;mf++)
        #pragma unroll
        for(int nf=0;nf<4;nf++)
          s[mf][nf] = __builtin_amdgcn_mfma_f32_16x16x32_bf16(qf[mf][ks], kf[nf], s[mf][nf], 0,0,0);
    }

    #pragma unroll
    for(int mf=0;mf<2;mf++){
      #pragma unroll
      for(int r=0;r<4;r++){
        float v = fmaxf(fmaxf(s[mf][0][r], s[mf][1][r]), fmaxf(s[mf][2][r], s[mf][3][r]));
        #pragma unroll
        for(int d=1; d<16; d<<=1) v = fmaxf(v, __shfl_xor(v, d));
        float nm = fmaxf(mrow[mf][r], v*SC);
        float fac = exp2f((mrow[mf][r]-nm)*L2E);
        mrow[mf][r] = nm;
        float rs = 0.f;
        #pragma unroll
        for(int nf=0;nf<4;nf++){
          float p = exp2f((s[mf][nf][r]*SC - nm)*L2E);
          s[mf][nf][r] = p;
          rs += p;
        }
        #pragma unroll
        for(int d=1; d<16; d<<=1) rs += __shfl_xor(rs, d);
        lrow[mf][r] = lrow[mf][r]*fac + rs;
        #pragma unroll
        for(int nf=0;nf<8;nf++) o[mf][nf][r] *= fac;
      }
    }

    #pragma unroll
    for(int mf=0;mf<2;mf++)
      #pragma unroll
      for(int nf=0;nf<4;nf++)
        #pragma unroll
        for(int r=0;r<4;r++)
          Pls[w*32 + mf*16 + lk*4 + r][nf*16 + lr] = usbf(s[mf][nf][r]);

    #pragma unroll
    for(int ks2=0; ks2<2; ks2++){
      bf16x8 pa[2];
      #pragma unroll
      for(int mf=0;mf<2;mf++)
        pa[mf] = *(const bf16x8*)&Pls[w*32 + mf*16 + lr][ks2*32 + lk*8];
      #pragma unroll
      for(int nf=0;nf<8;nf++){
        bf16x8 vf = *(const bf16x8*)&Vls[ks2][nf*16+lr][(lk*8) ^ rswz];
        #pragma unroll
        for(int mf=0;mf<2;mf++)
          o[mf][nf] = __builtin_amdgcn_mfma_f32_16x16x32_bf16(pa[mf], vf, o[mf][nf], 0,0,0);
      }
    }
  }

  #pragma unroll
  for(int mf=0;mf<2;mf++){
    float inv[4];
    #pragma unroll
    for(int r=0;r<4;r++) inv[r] = 1.f/lrow[mf][r];
    #pragma unroll
    for(int nf=0;nf<8;nf++){
      #pragma unroll
      for(int r=0;r<4;r++){
        size_t row = (size_t)qb*128 + w*32 + mf*16 + lk*4 + r;
        size_t col = (size_t)h*128 + nf*16 + lr;
        O[row*3072 + col] = usbf(o[mf][nf][r]*inv[r]);
      }
    }
  }
}

// ---------------- merged MFMA GEMM, bf16 A, fp32 W[K][N], 2-phase dbuf -------
// R8 schedule (known-good). Grid is FLAT in x = nBN * nMtot (nMtot=12 here),
// z = split-K. Flat id is XCD-swizzled (bijective: nwg % 8 == 0 at all call
// sites), then decoded bm-fastest so the 12 bm-tiles sharing one W panel are
// logically consecutive -> same XCD chunk -> W panel served from that XCD L2.
// mode 0: bf16 out (+bias)  mode 1: gelu -> bf16  mode 3: atomicAdd f32 gate*acc
__global__ __launch_bounds__(256,4) void k_gemmW(
    const unsigned short* __restrict__ A0, const unsigned short* __restrict__ A1, long lda,
    const float* __restrict__ W0, const float* __restrict__ W1, long ldw,
    const float* __restrict__ bias0, const float* __restrict__ bias1,
    void* __restrict__ C0, void* __restrict__ C1, long ldc,
    int nBN, int nM0, int K, int KS, int mode,
    const float* __restrict__ gate0, const float* __restrict__ gate1)
{
  __shared__ unsigned short Als[2][128*32];   // 2 x 8 KB, source-swizzled granules
  __shared__ unsigned short Bls[2][128*40];   // 2 x 10 KB, padded + XOR-swizzled
  const int t = threadIdx.x;

  // XCD swizzle + bm-fastest decode
  const int nwg = gridDim.x;
  const int chunk = nwg >> 3;
  const int logical = (blockIdx.x & 7)*chunk + (blockIdx.x >> 3);
  const int nMtot = nwg / nBN;
  int bm = logical % nMtot;
  const int bn = logical / nMtot;

  const bool sel1 = (bm >= nM0);
  const unsigned short* A = sel1 ? A1 : A0;
  const float* W  = sel1 ? W1 : W0;
  const float* bias = sel1 ? bias1 : bias0;
  const float* gate = sel1 ? gate1 : gate0;
  void* Cp = sel1 ? C1 : C0;
  if(sel1) bm -= nM0;
  const int zs = blockIdx.z;
  const int Kc = K / KS, kbeg = zs*Kc, kend = kbeg + Kc;

  const unsigned short* Ab = A + (size_t)bm*128*lda;
  const float* Wb = W + (size_t)bn*128;

  const int lane = t & 63, wid = t>>6, wr = wid>>1, wc = wid&1;
  const int lr = lane & 15, lk = lane>>4;
  const int srow = (lane>>2);
  const int soff = (((lane&3) ^ ((lane>>3)&3))*8);   // pre-swizzled A source chunk (R9-proven)
  const int aswz = ((lk ^ ((lr>>1)&3))*8);           // A read offset (shorts), 2-way
  const int bswz = (lk*8) ^ (((lr>>2)&3)<<3);        // B read offset (shorts)
  const int u = t&31, v = t>>5;
  const int wcol = (v*4) ^ ((u&3)<<3);               // B write col (shorts)

  f32x4 acc[4][4];
  #pragma unroll
  for(int i=0;i<4;i++)
    #pragma unroll
    for(int j=0;j<4;j++) acc[i][j] = {0.f,0.f,0.f,0.f};

  float4 wreg[4];

  // prologue: stage tile kbeg into buf 0
  gload16(Ab + (size_t)(     wid*16 + srow)*lda + kbeg + soff, &Als[0][(     wid*16)*32]);
  gload16(Ab + (size_t)(64 + wid*16 + srow)*lda + kbeg + soff, &Als[0][(64 + wid*16)*32]);
  #pragma unroll
  for(int j=0;j<4;j++)
    wreg[j] = *(const float4*)(Wb + (size_t)(kbeg + v*4 + j)*ldw + u*4);
  #pragma unroll
  for(int i=0;i<4;i++){
    u16x4 pk = { usbf(wreg[0][i]), usbf(wreg[1][i]), usbf(wreg[2][i]), usbf(wreg[3][i]) };
    *(u16x4*)&Bls[0][(u*4+i)*40 + wcol] = pk;
  }
  __syncthreads();

  unsigned short* AlsC = &Als[0][0]; unsigned short* AlsN = &Als[1][0];
  unsigned short* BlsC = &Bls[0][0]; unsigned short* BlsN = &Bls[1][0];

  for(int k0=kbeg; k0<kend; k0+=32){
    const bool has = (k0 + 32 < kend);
    if(has){
      int kn = k0 + 32;
      gload16(Ab + (size_t)(     wid*16 + srow)*lda + kn + soff, AlsN + (     wid*16)*32);
      gload16(Ab + (size_t)(64 + wid*16 + srow)*lda + kn + soff, AlsN + (64 + wid*16)*32);
      #pragma unroll
      for(int j=0;j<4;j++)
        wreg[j] = *(const float4*)(Wb + (size_t)(kn + v*4 + j)*ldw + u*4);
    }
    {
      bf16x8 af[4], bfr[4];
      #pragma unroll
      for(int mf=0;mf<4;mf++) af[mf]  = *(const bf16x8*)&AlsC[(wr*64 + mf*16 + lr)*32 + aswz];
      #pragma unroll
      for(int nf=0;nf<4;nf++) bfr[nf] = *(const bf16x8*)&BlsC[(wc*64 + nf*16 + lr)*40 + bswz];
      #pragma unroll
      for(int mf=0;mf<4;mf++)
        #pragma unroll
        for(int nf=0;nf<4;nf++)
          acc[mf][nf] = __builtin_amdgcn_mfma_f32_16x16x32_bf16(af[mf], bfr[nf], acc[mf][nf], 0,0,0);
    }
    if(has){
      #pragma unroll
      for(int i=0;i<4;i++){
        u16x4 pk = { usbf(wreg[0][i]), usbf(wreg[1][i]), usbf(wreg[2][i]), usbf(wreg[3][i]) };
        *(u16x4*)&BlsN[(u*4+i)*40 + wcol] = pk;
      }
    }
    __syncthreads();
    unsigned short* tmp;
    tmp = AlsC; AlsC = AlsN; AlsN = tmp;
    tmp = BlsC; BlsC = BlsN; BlsN = tmp;
  }

  unsigned short* C16 = (unsigned short*)Cp;
  float* C32 = (float*)Cp;
  #pragma unroll
  for(int mf=0;mf<4;mf++){
    #pragma unroll
    for(int nf=0;nf<4;nf++){
      #pragma unroll
      for(int r=0;r<4;r++){
        size_t row = (size_t)bm*128 + wr*64 + mf*16 + lk*4 + r;
        size_t col = (size_t)bn*128 + wc*64 + nf*16 + lr;
        float v2 = acc[mf][nf][r];
        if(mode==0){
          C16[row*ldc + col] = f2bf(v2 + (bias ? bias[col] : 0.f));
        } else if(mode==1){
          C16[row*ldc + col] = f2bf(gelu_tanh(v2 + (bias ? bias[col] : 0.f)));
        } else {
          float g = gate ? gate[col] : 1.f;
          atomicAdd(&C32[row*ldc + col], g*v2);
        }
      }
    }
  }
}

// ---------------- launch ----------------

extern "C" void kernel_launch(void* const* d_in, const int* in_sizes, int n_in,
                              void* d_out, int out_size, void* d_ws, size_t ws_size,
                              hipStream_t stream){
  const float* hidden_states = (const float*)d_in[0];
  const float* enc_states    = (const float*)d_in[1];
  const float* temb          = (const float*)d_in[3];
  const float* rope_cos      = (const float*)d_in[4];
  const float* rope_sin      = (const float*)d_in[5];
  const float* w_img_mod     = (const float*)d_in[6];
  const float* b_img_mod     = (const float*)d_in[7];
  const float* w_txt_mod     = (const float*)d_in[8];
  const float* b_txt_mod     = (const float*)d_in[9];
  const float* norm_q_w      = (const float*)d_in[10];
  const float* norm_k_w      = (const float*)d_in[11];
  const float* norm_aq_w     = (const float*)d_in[12];
  const float* norm_ak_w     = (const float*)d_in[13];
  const float* w_qkv   = (const float*)d_in[14];
  const float* b_qkv   = (const float*)d_in[15];
  const float* w_aqkv  = (const float*)d_in[16];
  const float* b_aqkv  = (const float*)d_in[17];
  const float* w_out_  = (const float*)d_in[18];
  const float* b_out_  = (const float*)d_in[19];
  const float* w_aout  = (const float*)d_in[20];
  const float* b_aout  = (const float*)d_in[21];
  const float* w_mlp1i = (const float*)d_in[22];
  const float* b_mlp1i = (const float*)d_in[23];
  const float* w_mlp2i = (const float*)d_in[24];
  const float* b_mlp2i = (const float*)d_in[25];
  const float* w_mlp1t = (const float*)d_in[26];
  const float* b_mlp1t = (const float*)d_in[27];
  const float* w_mlp2t = (const float*)d_in[28];
  const float* b_mlp2t = (const float*)d_in[29];

  char* ws = (char*)d_ws;
  float* mod    = (float*)(ws + 0);                        // 2*6*3072 f32
  float* silu_t = (float*)(ws + 147456);
  unsigned short* imgm = (unsigned short*)(ws + 159744);   // 1024x3072 bf16
  unsigned short* txtm = (unsigned short*)(ws + 6451200);  // 512x3072 bf16
  float* hid = (float*)(ws + 9596928);                     // 1024x3072 f32
  float* enc = (float*)(ws + 22179840);                    // 512x3072 f32
  unsigned short* Qb  = (unsigned short*)(ws + 47345664);  // 1536x3072 bf16
  unsigned short* Kb  = (unsigned short*)(ws + 56782848);
  unsigned short* Vb  = (unsigned short*)(ws + 66220032);  // dead after vtrans
  unsigned short* attnb = (unsigned short*)(ws + 66220032);// 1536x3072 bf16 (reuses Vb)
  unsigned short* VTb = (unsigned short*)(ws + 75657216);  // 24x128x1536 bf16
  unsigned short* mlphI = (unsigned short*)(ws + 103968768);// 1024x12288 bf16
  unsigned short* mlphT = (unsigned short*)(ws + 129134592);// 512x12288 bf16
  unsigned short* qkvi = (unsigned short*)(ws + 141717504);// 1024x9216 bf16
  unsigned short* qkvt = (unsigned short*)(ws + 160591872);// 512x9216 bf16

  float* out_enc = (float*)d_out;
  float* out_hid = (float*)d_out + (size_t)STX*DIMX;

  // modulation params
  k_silu<<<12,256,0,stream>>>(temb, silu_t);
  k_modinit<<<144,256,0,stream>>>(b_img_mod, b_txt_mod, mod);
  k_modgemv<<<288,256,0,stream>>>(w_img_mod, w_txt_mod, silu_t, mod);

  // LN + modulate (mod1), img+txt merged
  k_lnmod2<<<SQX,256,0,stream>>>(hidden_states, mod + 0, imgm,
                                 enc_states, mod + 18432, txtm, SIX);

  // QKV projections, img+txt merged (fp32 weights consumed directly)
  k_gemmW<<<dim3(72*12,1,1),256,0,stream>>>(imgm, txtm, 3072,
      w_qkv, w_aqkv, 9216, b_qkv, b_aqkv,
      qkvi, qkvt, 9216, 72, 8, 3072,1, 0, nullptr,nullptr);

  // RMS + RoPE -> Q,K,V [1536][24][128]; V transpose
  k_rmsrope<<<dim3(1536,24),64,0,stream>>>(qkvt, qkvi, norm_q_w, norm_k_w,
      norm_aq_w, norm_ak_w, rope_cos, rope_sin, Qb, Kb, Vb);
  k_vtrans<<<dim3(24,24),256,0,stream>>>(Vb, VTb);

  // fused flash attention -> attnb bf16
  k_fattn<<<dim3(12,24),256,0,stream>>>(Qb, Kb, VTb, attnb);

  // residual+gate1 inits, then merged out-projections (split-K atomics)
  k_initC2<<<4608,256,0,stream>>>(hid, hidden_states, mod + 2*3072, b_out_,
                                  enc, enc_states, mod + 18432 + 2*3072, b_aout, SIX);
  k_gemmW<<<dim3(24*12,1,4),256,0,stream>>>(attnb + (size_t)512*3072, attnb, 3072,
      w_out_, w_aout, 3072, nullptr, nullptr,
      hid, enc, 3072, 24, 8, 3072,4, 3, mod + 2*3072, mod + 18432 + 2*3072);

  // LN + modulate (mod2), merged
  k_lnmod2<<<SQX,256,0,stream>>>(hid, mod + 3*3072, imgm,
                                 enc, mod + 18432 + 3*3072, txtm, SIX);

  // MLP1 merged (gelu epilogue)
  k_gemmW<<<dim3(96*12,1,1),256,0,stream>>>(imgm, txtm, 3072,
      w_mlp1i, w_mlp1t, 12288, b_mlp1i, b_mlp1t,
      mlphI, mlphT, 12288, 96, 8, 3072,1, 1, nullptr,nullptr);

  // output inits, then MLP2 merged (split-K atomics into d_out)
  k_initC2<<<4608,256,0,stream>>>(out_hid, hid, mod + 5*3072, b_mlp2i,
                                  out_enc, enc, mod + 18432 + 5*3072, b_mlp2t, SIX);
  k_gemmW<<<dim3(24*12,1,4),256,0,stream>>>(mlphI, mlphT, 12288,
      w_mlp2i, w_mlp2t, 3072, nullptr, nullptr,
      out_hid, out_enc, 3072, 24, 8, 12288,4, 3, mod + 5*3072, mod + 18432 + 5*3072);
}

// Round 12
// 1099.819 us; speedup vs baseline: 1.6048x; 1.0210x over previous
//
#include <hip/hip_runtime.h>

#define DIMX 3072
#define STX 512
#define SIX 1024
#define SQX 1536
#define FFX 12288

typedef __attribute__((ext_vector_type(4))) float f32x4;
typedef __attribute__((ext_vector_type(8))) __bf16 bf16x8;
typedef __attribute__((ext_vector_type(4))) int i32x4;
typedef __attribute__((ext_vector_type(4))) unsigned short u16x4;

__device__ __forceinline__ unsigned short f2bf(float f){
  unsigned u = __builtin_bit_cast(unsigned, f);
  u += 0x7FFFu + ((u>>16)&1u);
  return (unsigned short)(u>>16);
}
__device__ __forceinline__ unsigned short usbf(float x){
  return __builtin_bit_cast(unsigned short, (__bf16)x);
}
__device__ __forceinline__ float bf2f(unsigned short h){
  unsigned u = ((unsigned)h)<<16;
  return __builtin_bit_cast(float, u);
}
__device__ __forceinline__ float gelu_tanh(float x){
  float x3 = x*x*x;
  float z = 0.7978845608028654f*(x + 0.044715f*x3);
  z = fminf(fmaxf(z, -15.f), 15.f);
  float e = exp2f(z*2.8853900817779268f);   // e^(2z)
  float th = (e-1.f)/(e+1.f);
  return 0.5f*x*(1.f+th);
}

// async global->LDS, 16B per lane; lds base must be wave-uniform
__device__ __forceinline__ void gload16(const void* g, void* l){
  __builtin_amdgcn_global_load_lds(
      (const __attribute__((address_space(1))) void*)g,
      (__attribute__((address_space(3))) void*)l,
      16, 0, 0);
}

// ---------------- small kernels ----------------

__global__ void k_silu(const float* __restrict__ temb, float* __restrict__ out){
  int i = blockIdx.x*256 + threadIdx.x;
  if(i < DIMX){
    float x = temb[i];
    out[i] = x / (1.f + exp2f(-x*1.4426950408889634f));
  }
}

__global__ void k_modinit(const float* __restrict__ b_img, const float* __restrict__ b_txt,
                          float* __restrict__ mod){
  int idx = blockIdx.x*256 + threadIdx.x;   // 0..36863
  int mat = idx / 18432; int r = idx % 18432;
  int i = r/6, j = r%6;
  const float* b = mat ? b_txt : b_img;
  mod[mat*18432 + j*3072 + i] = b[r];
}

__global__ void k_modgemv(const float* __restrict__ w_img, const float* __restrict__ w_txt,
                          const float* __restrict__ silu_t, float* __restrict__ mod){
  int bz = blockIdx.x;
  int ks = bz & 7; bz >>= 3;
  int nc = bz % 18; int mat = bz / 18;
  const float* W = mat ? w_txt : w_img;
  __shared__ float st[384];
  int k0 = ks*384;
  for(int i = threadIdx.x; i < 384; i += 256) st[i] = silu_t[k0+i];
  __syncthreads();
  int n0 = nc*1024 + threadIdx.x*4;
  float ax=0.f, ay=0.f, az=0.f, aw=0.f;
  const float* Wp = W + (size_t)k0*18432 + n0;
  #pragma unroll 4
  for(int k=0;k<384;k++){
    float4 w = *(const float4*)(Wp + (size_t)k*18432);
    float s = st[k];
    ax += s*w.x; ay += s*w.y; az += s*w.z; aw += s*w.w;
  }
  float* md = mod + mat*18432;
  float vals[4] = {ax, ay, az, aw};
  #pragma unroll
  for(int j=0;j<4;j++){
    int n = n0+j; int i = n/6, jj = n%6;
    atomicAdd(&md[jj*3072 + i], vals[j]);
  }
}

// merged init: rows [0,R0) -> set0, rows [R0,..) -> set1; out = res + gate*bias
__global__ void k_initC2(float* __restrict__ out0, const float* __restrict__ res0,
                         const float* __restrict__ gate0, const float* __restrict__ bias0,
                         float* __restrict__ out1, const float* __restrict__ res1,
                         const float* __restrict__ gate1, const float* __restrict__ bias1,
                         int R0){
  long i = ((long)blockIdx.x*256 + threadIdx.x)*4;
  int row = (int)(i / 3072);
  int col = (int)(i % 3072);
  const float* res; const float* gate; const float* bias; float* out;
  long off;
  if(row < R0){ res=res0; gate=gate0; bias=bias0; out=out0; off=i; }
  else        { res=res1; gate=gate1; bias=bias1; out=out1; off=i - (long)R0*3072; }
  float4 r = *(const float4*)(res + off);
  float4 g = *(const float4*)(gate + col);
  float4 b = *(const float4*)(bias + col);
  float4 o = {r.x + g.x*b.x, r.y + g.y*b.y, r.z + g.z*b.z, r.w + g.w*b.w};
  *(float4*)(out + off) = o;
}

// merged LayerNorm+modulate: block < R0 -> set0 else set1
__global__ void k_lnmod2(const float* __restrict__ x0, const float* __restrict__ modp0,
                         unsigned short* __restrict__ out0,
                         const float* __restrict__ x1, const float* __restrict__ modp1,
                         unsigned short* __restrict__ out1, int R0){
  int row = blockIdx.x, t = threadIdx.x;
  const float* x; const float* modp; unsigned short* out;
  if(row < R0){ x=x0; modp=modp0; out=out0; }
  else        { x=x1; modp=modp1; out=out1; row -= R0; }
  const float* xr = x + (size_t)row*DIMX;
  float4 v0 = *(const float4*)(xr + t*4);
  float4 v1 = *(const float4*)(xr + 1024 + t*4);
  float4 v2 = *(const float4*)(xr + 2048 + t*4);
  float s  = v0.x+v0.y+v0.z+v0.w + v1.x+v1.y+v1.z+v1.w + v2.x+v2.y+v2.z+v2.w;
  float s2 = v0.x*v0.x+v0.y*v0.y+v0.z*v0.z+v0.w*v0.w
           + v1.x*v1.x+v1.y*v1.y+v1.z*v1.z+v1.w*v1.w
           + v2.x*v2.x+v2.y*v2.y+v2.z*v2.z+v2.w*v2.w;
  #pragma unroll
  for(int o=32;o>0;o>>=1){ s += __shfl_xor(s,o); s2 += __shfl_xor(s2,o); }
  __shared__ float rs_[4], rs2_[4];
  int wid = t>>6;
  if((t&63)==0){ rs_[wid]=s; rs2_[wid]=s2; }
  __syncthreads();
  float S  = rs_[0]+rs_[1]+rs_[2]+rs_[3];
  float S2 = rs2_[0]+rs2_[1]+rs2_[2]+rs2_[3];
  float mu = S*(1.f/3072.f);
  float var = S2*(1.f/3072.f) - mu*mu;
  float rstd = rsqrtf(var + 1e-6f);
  #pragma unroll
  for(int j=0;j<3;j++){
    int c = j*1024 + t*4;
    float4 sh = *(const float4*)(modp + c);
    float4 sc = *(const float4*)(modp + 3072 + c);
    float4 xv = (j==0)?v0:((j==1)?v1:v2);
    unsigned short h0 = f2bf((xv.x-mu)*rstd*(sc.x+1.f)+sh.x);
    unsigned short h1 = f2bf((xv.y-mu)*rstd*(sc.y+1.f)+sh.y);
    unsigned short h2 = f2bf((xv.z-mu)*rstd*(sc.z+1.f)+sh.z);
    unsigned short h3 = f2bf((xv.w-mu)*rstd*(sc.w+1.f)+sh.w);
    unsigned long long pk = (unsigned long long)(h0 | ((unsigned)h1<<16))
                          | ((unsigned long long)(h2 | ((unsigned)h3<<16))<<32);
    *(unsigned long long*)(out + (size_t)row*DIMX + c) = pk;
  }
}

// RMSNorm(q,k) + RoPE, V passthrough. grid (1536, 24), block 64.
__global__ void k_rmsrope(const unsigned short* __restrict__ qkv_txt,
                          const unsigned short* __restrict__ qkv_img,
                          const float* __restrict__ nqw, const float* __restrict__ nkw,
                          const float* __restrict__ naqw, const float* __restrict__ nakw,
                          const float* __restrict__ cosb, const float* __restrict__ sinb,
                          unsigned short* __restrict__ Q, unsigned short* __restrict__ K,
                          unsigned short* __restrict__ V){
  int s = blockIdx.x, h = blockIdx.y, t = threadIdx.x;
  bool txt = s < STX;
  const unsigned short* src = txt ? (qkv_txt + (size_t)s*9216)
                                  : (qkv_img + (size_t)(s-STX)*9216);
  const float* qw = txt ? naqw : nqw;
  const float* kw = txt ? nakw : nkw;
  int d0 = 2*t;
  float q1 = bf2f(src[h*128 + d0]),        q2 = bf2f(src[h*128 + d0 + 1]);
  float k1 = bf2f(src[3072 + h*128 + d0]), k2 = bf2f(src[3072 + h*128 + d0 + 1]);
  float v1 = bf2f(src[6144 + h*128 + d0]), v2 = bf2f(src[6144 + h*128 + d0 + 1]);
  float sq = q1*q1 + q2*q2, sk = k1*k1 + k2*k2;
  #pragma unroll
  for(int o=32;o>0;o>>=1){ sq += __shfl_xor(sq,o); sk += __shfl_xor(sk,o); }
  float rq = rsqrtf(sq*(1.f/128.f) + 1e-6f);
  float rk = rsqrtf(sk*(1.f/128.f) + 1e-6f);
  q1 *= rq*qw[d0]; q2 *= rq*qw[d0+1];
  k1 *= rk*kw[d0]; k2 *= rk*kw[d0+1];
  float c1 = cosb[(size_t)s*128 + d0], c2 = cosb[(size_t)s*128 + d0 + 1];
  float s1 = sinb[(size_t)s*128 + d0], s2 = sinb[(size_t)s*128 + d0 + 1];
  float Q1 = q1*c1 - q2*s1, Q2 = q2*c2 + q1*s2;
  float K1 = k1*c1 - k2*s1, K2 = k2*c2 + k1*s2;
  size_t o = ((size_t)s*24 + h)*128 + d0;
  Q[o] = f2bf(Q1); Q[o+1] = f2bf(Q2);
  K[o] = f2bf(K1); K[o+1] = f2bf(K2);
  V[o] = f2bf(v1); V[o+1] = f2bf(v2);
}

// V[s][h][d] -> VT[h][d][s]. grid (24 s-tiles, 24 heads), block 256.
__global__ void k_vtrans(const unsigned short* __restrict__ V, unsigned short* __restrict__ VT){
  __shared__ unsigned short tile[64][136];
  int st = blockIdx.x, h = blockIdx.y, t = threadIdx.x;
  int s0 = st*64;
  {
    int s = t>>2;
    #pragma unroll
    for(int i=0;i<4;i++){
      int oct = ((t&3)<<2) + i;     // 0..15
      i32x4 d = *(const i32x4*)(V + ((size_t)(s0+s)*24 + h)*128 + oct*8);
      *(i32x4*)&tile[s][oct*8] = d;
    }
  }
  __syncthreads();
  {
    int d0 = t>>3; int strip = t&7;
    #pragma unroll
    for(int i=0;i<4;i++){
      int d = d0 + i*32;
      unsigned short h8[8];
      #pragma unroll
      for(int j=0;j<8;j++) h8[j] = tile[strip*8 + j][d];
      unsigned a0 = h8[0] | ((unsigned)h8[1]<<16);
      unsigned a1 = h8[2] | ((unsigned)h8[3]<<16);
      unsigned a2 = h8[4] | ((unsigned)h8[5]<<16);
      unsigned a3 = h8[6] | ((unsigned)h8[7]<<16);
      i32x4 dv = {(int)a0,(int)a1,(int)a2,(int)a3};
      *(i32x4*)(VT + ((size_t)h*128 + d)*1536 + s0 + strip*8) = dv;
    }
  }
}

// ---------------- fused flash attention ----------------
// grid (12 q-blocks, 24 heads), 256 threads (4 waves); each wave owns 32 q rows.
__global__ __launch_bounds__(256,2) void k_fattn(
    const unsigned short* __restrict__ Q,
    const unsigned short* __restrict__ Kb,
    const unsigned short* __restrict__ VT,
    unsigned short* __restrict__ O)
{
  __shared__ unsigned short Kls[4][64][32];
  __shared__ unsigned short Vls[2][128][32];
  __shared__ unsigned short Pls[128][72];
  const int t = threadIdx.x;
  const int qb = blockIdx.x, h = blockIdx.y;
  const int lane = t&63, w = t>>6;
  const int lr = lane&15, lk = lane>>4;
  const float SC  = 0.08838834764831845f;
  const float L2E = 1.4426950408889634f;
  const int schunk = ((lane&3) ^ ((lane>>2)&3))*8;   // pre-swizzled source chunk
  const int rswz   = ((lr&3)<<3);                    // read-side XOR (shorts)

  bf16x8 qf[2][4];
  {
    const unsigned short* qp = Q + ((size_t)(qb*128 + w*32 + lr)*3072) + h*128 + lk*8;
    #pragma unroll
    for(int mf=0;mf<2;mf++)
      #pragma unroll
      for(int ks=0;ks<4;ks++)
        qf[mf][ks] = *(const bf16x8*)(qp + (size_t)mf*16*3072 + ks*32);
  }

  f32x4 o[2][8];
  #pragma unroll
  for(int i=0;i<2;i++)
    #pragma unroll
    for(int j=0;j<8;j++) o[i][j] = (f32x4){0.f,0.f,0.f,0.f};
  float mrow[2][4], lrow[2][4];
  #pragma unroll
  for(int i=0;i<2;i++)
    #pragma unroll
    for(int r=0;r<4;r++){ mrow[i][r] = -3.0e30f; lrow[i][r] = 0.f; }

  for(int kv0=0; kv0<SQX; kv0+=64){
    __syncthreads();
    {
      const unsigned short* kp = Kb + ((size_t)(kv0 + (lane>>2))*3072) + h*128 + w*32 + schunk;
      #pragma unroll
      for(int i=0;i<4;i++)
        gload16(kp + (size_t)i*16*3072, &Kls[w][i*16][0]);
    }
    {
      int c = w>>1;
      const unsigned short* vp = VT + ((size_t)(h*128 + (w&1)*64 + (lane>>2)))*1536 + kv0 + c*32 + schunk;
      #pragma unroll
      for(int j=0;j<4;j++)
        gload16(vp + (size_t)j*16*1536, &Vls[c][(w&1)*64 + j*16][0]);
    }
    __syncthreads();

    f32x4 s[2][4];
    #pragma unroll
    for(int mf=0;mf<2;mf++)
      #pragma unroll
      for(int nf=0;nf<4;nf++) s[mf][nf] = (f32x4){0.f,0.f,0.f,0.f};
    #pragma unroll
    for(int ks=0;ks<4;ks++){
      bf16x8 kf[4];
      #pragma unroll
      for(int nf=0;nf<4;nf++) kf[nf] = *(const bf16x8*)&Kls[ks][nf*16+lr][(lk*8) ^ rswz];
      #pragma unroll
      for(int mf=0;mf<2;mf++)
        #pragma unroll
        for(int nf=0;nf<4;nf++)
          s[mf][nf] = __builtin_amdgcn_mfma_f32_16x16x32_bf16(qf[mf][ks], kf[nf], s[mf][nf], 0,0,0);
    }

    #pragma unroll
    for(int mf=0;mf<2;mf++){
      #pragma unroll
      for(int r=0;r<4;r++){
        float v = fmaxf(fmaxf(s[mf][0][r], s[mf][1][r]), fmaxf(s[mf][2][r], s[mf][3][r]));
        #pragma unroll
        for(int d=1; d<16; d<<=1) v = fmaxf(v, __shfl_xor(v, d));
        float nm = fmaxf(mrow[mf][r], v*SC);
        float fac = exp2f((mrow[mf][r]-nm)*L2E);
        mrow[mf][r] = nm;
        float rs = 0.f;
        #pragma unroll
        for(int nf=0;nf<4;nf++){
          float p = exp2f((s[mf][nf][r]*SC - nm)*L2E);
          s[mf][nf][r] = p;
          rs += p;
        }
        #pragma unroll
        for(int d=1; d<16; d<<=1) rs += __shfl_xor(rs, d);
        lrow[mf][r] = lrow[mf][r]*fac + rs;
        #pragma unroll
        for(int nf=0;nf<8;nf++) o[mf][nf][r] *= fac;
      }
    }

    #pragma unroll
    for(int mf=0;mf<2;mf++)
      #pragma unroll
      for(int nf=0;nf<4;nf++)
        #pragma unroll
        for(int r=0;r<4;r++)
          Pls[w*32 + mf*16 + lk*4 + r][nf*16 + lr] = usbf(s[mf][nf][r]);

    #pragma unroll
    for(int ks2=0; ks2<2; ks2++){
      bf16x8 pa[2];
      #pragma unroll
      for(int mf=0;mf<2;mf++)
        pa[mf] = *(const bf16x8*)&Pls[w*32 + mf*16 + lr][ks2*32 + lk*8];
      #pragma unroll
      for(int nf=0;nf<8;nf++){
        bf16x8 vf = *(const bf16x8*)&Vls[ks2][nf*16+lr][(lk*8) ^ rswz];
        #pragma unroll
        for(int mf=0;mf<2;mf++)
          o[mf][nf] = __builtin_amdgcn_mfma_f32_16x16x32_bf16(pa[mf], vf, o[mf][nf], 0,0,0);
      }
    }
  }

  #pragma unroll
  for(int mf=0;mf<2;mf++){
    float inv[4];
    #pragma unroll
    for(int r=0;r<4;r++) inv[r] = 1.f/lrow[mf][r];
    #pragma unroll
    for(int nf=0;nf<8;nf++){
      #pragma unroll
      for(int r=0;r<4;r++){
        size_t row = (size_t)qb*128 + w*32 + mf*16 + lk*4 + r;
        size_t col = (size_t)h*128 + nf*16 + lr;
        O[row*3072 + col] = usbf(o[mf][nf][r]*inv[r]);
      }
    }
  }
}

// ---------------- merged MFMA GEMM, bf16 A, fp32 W[K][N], 2-phase dbuf -------
// R8 schedule and grid (known-best). bm-tiles [0,nM0) -> set0, rest -> set1.
// mode 0: bf16 out (+bias)  mode 1: gelu -> bf16  mode 3: atomicAdd f32 gate*acc
__global__ __launch_bounds__(256,4) void k_gemmW(
    const unsigned short* __restrict__ A0, const unsigned short* __restrict__ A1, long lda,
    const float* __restrict__ W0, const float* __restrict__ W1, long ldw,
    const float* __restrict__ bias0, const float* __restrict__ bias1,
    void* __restrict__ C0, void* __restrict__ C1, long ldc,
    int nM0, int K, int KS, int mode,
    const float* __restrict__ gate0, const float* __restrict__ gate1)
{
  __shared__ unsigned short Als[2][128*32];   // 2 x 8 KB, source-swizzled granules
  __shared__ unsigned short Bls[2][128*40];   // 2 x 10 KB, padded + XOR-swizzled
  const int t = threadIdx.x;
  const int bn = blockIdx.x;
  int bm = blockIdx.y;
  const bool sel1 = (bm >= nM0);
  const unsigned short* A = sel1 ? A1 : A0;
  const float* W  = sel1 ? W1 : W0;
  const float* bias = sel1 ? bias1 : bias0;
  const float* gate = sel1 ? gate1 : gate0;
  void* Cp = sel1 ? C1 : C0;
  if(sel1) bm -= nM0;
  const int zs = blockIdx.z;
  const int Kc = K / KS, kbeg = zs*Kc, kend = kbeg + Kc;

  const unsigned short* Ab = A + (size_t)bm*128*lda;
  const float* Wb = W + (size_t)bn*128;

  const int lane = t & 63, wid = t>>6, wr = wid>>1, wc = wid&1;
  const int lr = lane & 15, lk = lane>>4;
  const int srow = (lane>>2);
  const int soff = (((lane&3) ^ ((lane>>3)&3))*8);   // pre-swizzled A source chunk
  const int aswz = ((lk ^ ((lr>>1)&3))*8);           // A read offset (shorts), 2-way
  const int bswz = (lk*8) ^ (((lr>>2)&3)<<3);        // B read offset (shorts)
  const int u = t&31, v = t>>5;
  const int wcol = (v*4) ^ ((u&3)<<3);               // B write col (shorts)

  f32x4 acc[4][4];
  #pragma unroll
  for(int i=0;i<4;i++)
    #pragma unroll
    for(int j=0;j<4;j++) acc[i][j] = {0.f,0.f,0.f,0.f};

  float4 wreg[4];

  // prologue: stage tile kbeg into buf 0
  gload16(Ab + (size_t)(     wid*16 + srow)*lda + kbeg + soff, &Als[0][(     wid*16)*32]);
  gload16(Ab + (size_t)(64 + wid*16 + srow)*lda + kbeg + soff, &Als[0][(64 + wid*16)*32]);
  #pragma unroll
  for(int j=0;j<4;j++)
    wreg[j] = *(const float4*)(Wb + (size_t)(kbeg + v*4 + j)*ldw + u*4);
  #pragma unroll
  for(int i=0;i<4;i++){
    u16x4 pk = { usbf(wreg[0][i]), usbf(wreg[1][i]), usbf(wreg[2][i]), usbf(wreg[3][i]) };
    *(u16x4*)&Bls[0][(u*4+i)*40 + wcol] = pk;
  }
  __syncthreads();

  unsigned short* AlsC = &Als[0][0]; unsigned short* AlsN = &Als[1][0];
  unsigned short* BlsC = &Bls[0][0]; unsigned short* BlsN = &Bls[1][0];

  for(int k0=kbeg; k0<kend; k0+=32){
    const bool has = (k0 + 32 < kend);
    if(has){
      int kn = k0 + 32;
      gload16(Ab + (size_t)(     wid*16 + srow)*lda + kn + soff, AlsN + (     wid*16)*32);
      gload16(Ab + (size_t)(64 + wid*16 + srow)*lda + kn + soff, AlsN + (64 + wid*16)*32);
      #pragma unroll
      for(int j=0;j<4;j++)
        wreg[j] = *(const float4*)(Wb + (size_t)(kn + v*4 + j)*ldw + u*4);
    }
    {
      bf16x8 af[4], bfr[4];
      #pragma unroll
      for(int mf=0;mf<4;mf++) af[mf]  = *(const bf16x8*)&AlsC[(wr*64 + mf*16 + lr)*32 + aswz];
      #pragma unroll
      for(int nf=0;nf<4;nf++) bfr[nf] = *(const bf16x8*)&BlsC[(wc*64 + nf*16 + lr)*40 + bswz];
      #pragma unroll
      for(int mf=0;mf<4;mf++)
        #pragma unroll
        for(int nf=0;nf<4;nf++)
          acc[mf][nf] = __builtin_amdgcn_mfma_f32_16x16x32_bf16(af[mf], bfr[nf], acc[mf][nf], 0,0,0);
    }
    if(has){
      #pragma unroll
      for(int i=0;i<4;i++){
        u16x4 pk = { usbf(wreg[0][i]), usbf(wreg[1][i]), usbf(wreg[2][i]), usbf(wreg[3][i]) };
        *(u16x4*)&BlsN[(u*4+i)*40 + wcol] = pk;
      }
    }
    __syncthreads();
    unsigned short* tmp;
    tmp = AlsC; AlsC = AlsN; AlsN = tmp;
    tmp = BlsC; BlsC = BlsN; BlsN = tmp;
  }

  unsigned short* C16 = (unsigned short*)Cp;
  float* C32 = (float*)Cp;
  #pragma unroll
  for(int mf=0;mf<4;mf++){
    #pragma unroll
    for(int nf=0;nf<4;nf++){
      #pragma unroll
      for(int r=0;r<4;r++){
        size_t row = (size_t)bm*128 + wr*64 + mf*16 + lk*4 + r;
        size_t col = (size_t)bn*128 + wc*64 + nf*16 + lr;
        float v2 = acc[mf][nf][r];
        if(mode==0){
          C16[row*ldc + col] = f2bf(v2 + (bias ? bias[col] : 0.f));
        } else if(mode==1){
          C16[row*ldc + col] = f2bf(gelu_tanh(v2 + (bias ? bias[col] : 0.f)));
        } else {
          float g = gate ? gate[col] : 1.f;
          atomicAdd(&C32[row*ldc + col], g*v2);
        }
      }
    }
  }
}

// ---------------- launch ----------------

extern "C" void kernel_launch(void* const* d_in, const int* in_sizes, int n_in,
                              void* d_out, int out_size, void* d_ws, size_t ws_size,
                              hipStream_t stream){
  const float* hidden_states = (const float*)d_in[0];
  const float* enc_states    = (const float*)d_in[1];
  const float* temb          = (const float*)d_in[3];
  const float* rope_cos      = (const float*)d_in[4];
  const float* rope_sin      = (const float*)d_in[5];
  const float* w_img_mod     = (const float*)d_in[6];
  const float* b_img_mod     = (const float*)d_in[7];
  const float* w_txt_mod     = (const float*)d_in[8];
  const float* b_txt_mod     = (const float*)d_in[9];
  const float* norm_q_w      = (const float*)d_in[10];
  const float* norm_k_w      = (const float*)d_in[11];
  const float* norm_aq_w     = (const float*)d_in[12];
  const float* norm_ak_w     = (const float*)d_in[13];
  const float* w_qkv   = (const float*)d_in[14];
  const float* b_qkv   = (const float*)d_in[15];
  const float* w_aqkv  = (const float*)d_in[16];
  const float* b_aqkv  = (const float*)d_in[17];
  const float* w_out_  = (const float*)d_in[18];
  const float* b_out_  = (const float*)d_in[19];
  const float* w_aout  = (const float*)d_in[20];
  const float* b_aout  = (const float*)d_in[21];
  const float* w_mlp1i = (const float*)d_in[22];
  const float* b_mlp1i = (const float*)d_in[23];
  const float* w_mlp2i = (const float*)d_in[24];
  const float* b_mlp2i = (const float*)d_in[25];
  const float* w_mlp1t = (const float*)d_in[26];
  const float* b_mlp1t = (const float*)d_in[27];
  const float* w_mlp2t = (const float*)d_in[28];
  const float* b_mlp2t = (const float*)d_in[29];

  char* ws = (char*)d_ws;
  float* mod    = (float*)(ws + 0);                        // 2*6*3072 f32
  float* silu_t = (float*)(ws + 147456);
  unsigned short* imgm = (unsigned short*)(ws + 159744);   // 1024x3072 bf16
  unsigned short* txtm = (unsigned short*)(ws + 6451200);  // 512x3072 bf16
  float* hid = (float*)(ws + 9596928);                     // 1024x3072 f32
  float* enc = (float*)(ws + 22179840);                    // 512x3072 f32
  unsigned short* Qb  = (unsigned short*)(ws + 47345664);  // 1536x3072 bf16
  unsigned short* Kb  = (unsigned short*)(ws + 56782848);
  unsigned short* Vb  = (unsigned short*)(ws + 66220032);  // dead after vtrans
  unsigned short* attnb = (unsigned short*)(ws + 66220032);// 1536x3072 bf16 (reuses Vb)
  unsigned short* VTb = (unsigned short*)(ws + 75657216);  // 24x128x1536 bf16
  unsigned short* mlphI = (unsigned short*)(ws + 103968768);// 1024x12288 bf16
  unsigned short* mlphT = (unsigned short*)(ws + 129134592);// 512x12288 bf16
  unsigned short* qkvi = (unsigned short*)(ws + 141717504);// 1024x9216 bf16
  unsigned short* qkvt = (unsigned short*)(ws + 160591872);// 512x9216 bf16

  float* out_enc = (float*)d_out;
  float* out_hid = (float*)d_out + (size_t)STX*DIMX;

  // modulation params
  k_silu<<<12,256,0,stream>>>(temb, silu_t);
  k_modinit<<<144,256,0,stream>>>(b_img_mod, b_txt_mod, mod);
  k_modgemv<<<288,256,0,stream>>>(w_img_mod, w_txt_mod, silu_t, mod);

  // LN + modulate (mod1), img+txt merged
  k_lnmod2<<<SQX,256,0,stream>>>(hidden_states, mod + 0, imgm,
                                 enc_states, mod + 18432, txtm, SIX);

  // QKV projections, img+txt merged (fp32 weights consumed directly)
  k_gemmW<<<dim3(72,12,1),256,0,stream>>>(imgm, txtm, 3072,
      w_qkv, w_aqkv, 9216, b_qkv, b_aqkv,
      qkvi, qkvt, 9216, 8, 3072,1, 0, nullptr,nullptr);

  // RMS + RoPE -> Q,K,V [1536][24][128]; V transpose
  k_rmsrope<<<dim3(1536,24),64,0,stream>>>(qkvt, qkvi, norm_q_w, norm_k_w,
      norm_aq_w, norm_ak_w, rope_cos, rope_sin, Qb, Kb, Vb);
  k_vtrans<<<dim3(24,24),256,0,stream>>>(Vb, VTb);

  // fused flash attention -> attnb bf16
  k_fattn<<<dim3(12,24),256,0,stream>>>(Qb, Kb, VTb, attnb);

  // residual+gate1 inits, then merged out-projections (split-K atomics)
  k_initC2<<<4608,256,0,stream>>>(hid, hidden_states, mod + 2*3072, b_out_,
                                  enc, enc_states, mod + 18432 + 2*3072, b_aout, SIX);
  k_gemmW<<<dim3(24,12,4),256,0,stream>>>(attnb + (size_t)512*3072, attnb, 3072,
      w_out_, w_aout, 3072, nullptr, nullptr,
      hid, enc, 3072, 8, 3072,4, 3, mod + 2*3072, mod + 18432 + 2*3072);

  // LN + modulate (mod2), merged
  k_lnmod2<<<SQX,256,0,stream>>>(hid, mod + 3*3072, imgm,
                                 enc, mod + 18432 + 3*3072, txtm, SIX);

  // MLP1 merged (gelu epilogue)
  k_gemmW<<<dim3(96,12,1),256,0,stream>>>(imgm, txtm, 3072,
      w_mlp1i, w_mlp1t, 12288, b_mlp1i, b_mlp1t,
      mlphI, mlphT, 12288, 8, 3072,1, 1, nullptr,nullptr);

  // output inits, then MLP2 merged (split-K atomics into d_out)
  k_initC2<<<4608,256,0,stream>>>(out_hid, hid, mod + 5*3072, b_mlp2i,
                                  out_enc, enc, mod + 18432 + 5*3072, b_mlp2t, SIX);
  k_gemmW<<<dim3(24,12,4),256,0,stream>>>(mlphI, mlphT, 12288,
      w_mlp2i, w_mlp2t, 3072, nullptr, nullptr,
      out_hid, out_enc, 3072, 8, 12288,4, 3, mod + 5*3072, mod + 18432 + 5*3072);
}